// Round 9
// baseline (46.986 us; speedup 1.0000x reference)
//
#include <hip/hip_runtime.h>

#define NB 2
#define NT 4
#define NN 4096
#define NBT (NB*NT)
#define TOTAL (NBT*NN)        // 32768 points per tensor
#define BIGF 1e10f
#define THRESHF 1e9f
#define NEGF (-1e10f)

typedef __attribute__((ext_vector_type(8)))  short s16x8;
typedef __attribute__((ext_vector_type(16))) float f32x16;

// round-to-nearest-even f32 -> bf16 (raw bits)
__device__ inline unsigned short f2bf(float f) {
    unsigned u = __float_as_uint(f);
    u += 0x7fffu + ((u >> 16) & 1u);
    return (unsigned short)(u >> 16);
}
// split x into bf16 hi + bf16 lo (lo = rn(x - hi)); hi+lo represents x to ~2^-17 rel
__device__ inline void split2(float x, unsigned short& hi, unsigned short& lo) {
    hi = f2bf(x);
    float fh = __uint_as_float(((unsigned)hi) << 16);
    lo = f2bf(x - fh);
}
__device__ inline s16x8 mk8(unsigned short a, unsigned short b, unsigned short c, unsigned short d,
                            unsigned short e, unsigned short f, unsigned short g, unsigned short h) {
    return (s16x8){(short)a,(short)b,(short)c,(short)d,(short)e,(short)f,(short)g,(short)h};
}

// Synthetic K=13 (slots 13..15 zero) on mfma_f32_32x32x16_bf16 (verified r6/r7/r8, absmax 0.0).
// Row point p (split pa+pb), col point t (u = -2t split ua+ub), wp=||p||^2, wt=||t||^2+bias:
//   row chunk0: pax,pay,paz,pbx,pby,pbz,pax,pay   chunk1: paz,one,one,wph,wpl,0,0,0
//   col chunk0: uax,uay,uaz,uax,uay,uaz,ubx,uby   chunk1: ubz,wth,wtl,one,one,0,0,0
// => D[r,c] = wp + wt - 2 p.t  (lo*lo term dropped, err ~4e-6)
// A/B frag: lane l -> row/col l&31, k-chunk l>>5.
// C/D: col = lane&31, row = (reg&3) + 8*(reg>>2) + 4*(lane>>5)

// ws layout: minp[TOTAL] u32 | mint[TOTAL] u32 | cnt[16] u32
// minp/mint memset to 0xFF (=+huge float) each call; cnt memset to 0; out memset to 0.

// Single fused kernel. grid (4 cc, 16 rc, 16 bt*dir) = 1024 blocks, 256 thr = 4 waves,
// ~34 KB LDS, 4 blocks/CU. Each block: stage 1024 col packs in LDS, MFMA row-min over
// its 256 rows x 1024 cols, LDS-transpose epilogue, global atomicMin publish.
// Last block of each bt (counter==127) runs that bt's finalize inline (overlapped).
__global__ __launch_bounds__(256, 4) void hybrid_kernel(
    const float* __restrict__ pred, const float* __restrict__ targ,
    const int* __restrict__ ic, const int* __restrict__ pad, const int* __restrict__ vis,
    unsigned* __restrict__ minp, unsigned* __restrict__ mint,
    unsigned* __restrict__ cnt, float* __restrict__ out)
{
    // 2048 B-records (32 KB) for staging; reused as 4x64x33 f32 (33792 B) in epilogue
    __shared__ __align__(16) char ldsraw[33792];
    __shared__ float redA[4][5];
    __shared__ float redB[4][4];
    __shared__ int sflag;
    s16x8* ldsB = (s16x8*)ldsraw;

    const int tid  = threadIdx.x;
    const int lane = tid & 63;
    const int w    = tid >> 6;
    const int cc   = blockIdx.x;
    const int rc   = blockIdx.y;
    const int z    = blockIdx.z;
    const int bt   = z >> 1;
    const int dir  = z & 1;
    const int b    = bt >> 2;

    const float* __restrict__ rowraw = dir ? targ : pred;
    const float* __restrict__ colraw = dir ? pred : targ;
    unsigned* outp = dir ? mint : minp;
    const unsigned short one = 0x3F80;

    // ---- stage 1024 column packs into LDS (computed from raw floats + mask) ----
    #pragma unroll
    for (int r = 0; r < 4; ++r) {
        int nloc = r*256 + tid;                 // local col 0..1023
        int n    = cc*1024 + nloc;              // col within bt
        int gi   = bt*NN + n;
        bool m = (ic[b*NN + n] == 0) && (pad[b*NN + n] != 0) && (vis[gi] != 0);
        float bias = m ? 0.0f : BIGF;
        float x = colraw[3*gi], y = colraw[3*gi+1], zc = colraw[3*gi+2];
        unsigned short ux,uy,uz,vx,vy,vz,ch,cl;
        split2(-2.0f*x,ux,vx); split2(-2.0f*y,uy,vy); split2(-2.0f*zc,uz,vz);
        float wn = fmaf(x,x, fmaf(y,y, zc*zc));
        split2(wn + bias, ch, cl);
        int tile = nloc >> 5;
        int c32  = tid & 31;                    // == nloc & 31
        ldsB[tile*64 + c32]      = mk8(ux,uy,uz,ux,uy,uz,vx,vy);
        ldsB[tile*64 + 32 + c32] = mk8(vz,ch,cl,one,one,0,0,0);
    }

    // ---- row fragments in registers (2 x 32-row tiles per wave) ----
    const int h  = lane >> 5;       // k-chunk
    const int c  = lane & 31;       // row within tile
    const int n0 = rc*256 + w*64;
    s16x8 a[2];
    #pragma unroll
    for (int rt = 0; rt < 2; ++rt) {
        int row = bt*NN + n0 + rt*32 + c;
        float x = rowraw[3*row], y = rowraw[3*row+1], zc = rowraw[3*row+2];
        unsigned short ax,ay,az,bx,by,bz,wh,wl;
        split2(x,ax,bx); split2(y,ay,by); split2(zc,az,bz);
        float wn = fmaf(x,x, fmaf(y,y, zc*zc));
        split2(wn, wh, wl);
        a[rt] = h ? mk8(az,one,one,wh,wl,0,0,0) : mk8(ax,ay,az,bx,by,bz,ax,ay);
    }

    __syncthreads();

    f32x16 zf, mm[2];
    #pragma unroll
    for (int q = 0; q < 16; ++q) { zf[q] = 0.0f; mm[0][q] = 3.4e38f; mm[1][q] = 3.4e38f; }

    #pragma unroll 1
    for (int tp = 0; tp < 16; ++tp) {
        s16x8 b0 = ldsB[tp*128 + lane];
        s16x8 b1 = ldsB[tp*128 + 64 + lane];
        #pragma unroll
        for (int rt = 0; rt < 2; ++rt) {
            f32x16 D0 = __builtin_amdgcn_mfma_f32_32x32x16_bf16(a[rt], b0, zf, 0, 0, 0);
            f32x16 D1 = __builtin_amdgcn_mfma_f32_32x32x16_bf16(a[rt], b1, zf, 0, 0, 0);
            #pragma unroll
            for (int q = 0; q < 16; ++q)
                mm[rt][q] = fminf(fminf(D0[q], D1[q]), mm[rt][q]);   // v_min3
        }
    }

    // ---- LDS-transpose epilogue: wave-private [64 rows][33 stride] f32 region ----
    __syncthreads();                 // everyone done reading staged B
    float* fbuf = (float*)ldsraw;
    const int wbase = w * 2112;      // 64*33
    #pragma unroll
    for (int rt = 0; rt < 2; ++rt) {
        #pragma unroll
        for (int q = 0; q < 16; ++q) {
            int rl = rt*32 + (q & 3) + 8*(q >> 2) + 4*h;   // row-local 0..63
            fbuf[wbase + rl*33 + c] = mm[rt][q];
        }
    }
    // lane l owns row-local l: tree-min its 32 column partials (conflict-free stride 33)
    const float* rowp = fbuf + wbase + lane*33;
    float v = 3.4e38f;
    #pragma unroll
    for (int k = 0; k < 32; ++k) v = fminf(v, rowp[k]);
    float xv = fmaxf(v, 0.0f);
    unsigned bits = __float_as_uint(xv);
    if (!(xv == xv))         bits = __float_as_uint(BIGF);  // NaN guard
    if (bits == 0x80000000u) bits = 0u;                     // -0 -> +0
    atomicMin(&outp[bt*NN + n0 + lane], bits);              // device-scope combine

    // ---- completion counting; last block of this bt finalizes ----
    __syncthreads();                 // drain this block's atomics (vmcnt(0) before barrier)
    if (tid == 0) {
        __threadfence();             // release: publishes visible before count
        unsigned old = atomicAdd(&cnt[bt], 1u);
        sflag = (old == 127u) ? 1 : 0;
    }
    __syncthreads();
    if (!sflag) return;              // uniform per block: barrier-safe below
    __threadfence();                 // acquire: see all blocks' published mins

    // ---- finalize for this bt: 256 threads, 16 elems each ----
    const uint4* mp4 = (const uint4*)(minp + bt*NN);
    const uint4* mt4 = (const uint4*)(mint + bt*NN);
    const int4*  ic4p  = (const int4*)(ic  + b*NN);
    const int4*  pad4p = (const int4*)(pad + b*NN);
    const int4*  vis4p = (const int4*)(vis + bt*NN);

    float hp[16], ht[16];
    float nv = 0.f, scdp = 0.f, scdt = 0.f, mhp = NEGF, mht = NEGF;
    #pragma unroll
    for (int g = 0; g < 4; ++g) {
        int i4 = tid + g*256;
        uint4 p4 = mp4[i4];
        uint4 t4 = mt4[i4];
        int4 i4v = ic4p[i4];
        int4 a4v = pad4p[i4];
        int4 v4v = vis4p[i4];
        unsigned pu[4] = { p4.x, p4.y, p4.z, p4.w };
        unsigned tu[4] = { t4.x, t4.y, t4.z, t4.w };
        int icv[4]  = { i4v.x, i4v.y, i4v.z, i4v.w };
        int padv[4] = { a4v.x, a4v.y, a4v.z, a4v.w };
        int visv[4] = { v4v.x, v4v.y, v4v.z, v4v.w };
        #pragma unroll
        for (int e = 0; e < 4; ++e) {
            bool m = (icv[e] == 0) && (padv[e] != 0) && (visv[e] != 0);
            float mp = __uint_as_float(pu[e]);
            float mt = __uint_as_float(tu[e]);
            if (!(mp <= 2e10f)) mp = BIGF;   // NaN/garbage/unwritten guard
            if (!(mt <= 2e10f)) mt = BIGF;
            float hpv = m ? fminf(mp, THRESHF) : NEGF;
            float htv = m ? fminf(mt, THRESHF) : NEGF;
            hp[g*4+e] = hpv; ht[g*4+e] = htv;
            if (m) {
                nv += 1.f;
                scdp += (mp > THRESHF) ? 0.f : mp;
                scdt += (mt > THRESHF) ? 0.f : mt;
                mhp = fmaxf(mhp, hpv);
                mht = fmaxf(mht, htv);
            }
        }
    }

    #pragma unroll
    for (int o = 32; o > 0; o >>= 1) {
        nv   += __shfl_xor(nv, o);
        scdp += __shfl_xor(scdp, o);
        scdt += __shfl_xor(scdt, o);
        mhp   = fmaxf(mhp, __shfl_xor(mhp, o));
        mht   = fmaxf(mht, __shfl_xor(mht, o));
    }
    if (lane == 0) {
        redA[w][0] = nv; redA[w][1] = scdp; redA[w][2] = scdt;
        redA[w][3] = mhp; redA[w][4] = mht;
    }
    __syncthreads();
    nv   = redA[0][0] + redA[1][0] + redA[2][0] + redA[3][0];
    scdp = redA[0][1] + redA[1][1] + redA[2][1] + redA[3][1];
    scdt = redA[0][2] + redA[1][2] + redA[2][2] + redA[3][2];
    mhp  = fmaxf(fmaxf(redA[0][3], redA[1][3]), fmaxf(redA[2][3], redA[3][3]));
    mht  = fmaxf(fmaxf(redA[0][4], redA[1][4]), fmaxf(redA[2][4], redA[3][4]));
    __syncthreads();

    float Zp = 0.f, Sp = 0.f, Zt = 0.f, St = 0.f;
    #pragma unroll
    for (int k = 0; k < 16; ++k) {
        float hpv = hp[k];
        if (hpv > -THRESHF) { float x = __expf((hpv - mhp) * 10.0f); Zp += x; Sp += hpv * x; }
        float htv = ht[k];
        if (htv > -THRESHF) { float x = __expf((htv - mht) * 10.0f); Zt += x; St += htv * x; }
    }
    #pragma unroll
    for (int o = 32; o > 0; o >>= 1) {
        Zp += __shfl_xor(Zp, o);
        Sp += __shfl_xor(Sp, o);
        Zt += __shfl_xor(Zt, o);
        St += __shfl_xor(St, o);
    }
    if (lane == 0) {
        redB[w][0] = Zp; redB[w][1] = Sp; redB[w][2] = Zt; redB[w][3] = St;
    }
    __syncthreads();
    if (tid == 0) {
        Zp = redB[0][0] + redB[1][0] + redB[2][0] + redB[3][0];
        Sp = redB[0][1] + redB[1][1] + redB[2][1] + redB[3][1];
        Zt = redB[0][2] + redB[1][2] + redB[2][2] + redB[3][2];
        St = redB[0][3] + redB[1][3] + redB[2][3] + redB[3][3];
        float nvm = fmaxf(nv, 1.f);
        float cd  = scdp / nvm + scdt / nvm;
        float sp  = (nv > 0.f) ? (Sp / Zp) : 0.f;
        float st  = (nv > 0.f) ? (St / Zt) : 0.f;
        float hd  = fmaxf(sp, st);
        atomicAdd(out, (0.5f * cd + 0.5f * hd) * 0.125f);
    }
}

extern "C" void kernel_launch(void* const* d_in, const int* in_sizes, int n_in,
                              void* d_out, int out_size, void* d_ws, size_t ws_size,
                              hipStream_t stream)
{
    const float* pred = (const float*)d_in[0];
    const float* targ = (const float*)d_in[1];
    const int*   ic   = (const int*)d_in[2];
    const int*   pad  = (const int*)d_in[3];
    const int*   vis  = (const int*)d_in[4];
    float* out = (float*)d_out;

    unsigned* minp = (unsigned*)d_ws;             // TOTAL u32
    unsigned* mint = minp + TOTAL;                // TOTAL u32
    unsigned* cnt  = mint + TOTAL;                // 16 u32

    // init: mins = +huge (0xFF bytes), counters = 0, out = 0  (all graph-capturable)
    hipMemsetAsync(minp, 0xFF, (size_t)2 * TOTAL * 4, stream);
    hipMemsetAsync(cnt, 0, 16 * 4, stream);
    hipMemsetAsync(out, 0, 4, stream);

    dim3 grid(4, 16, 16);
    hybrid_kernel<<<grid, 256, 0, stream>>>(pred, targ, ic, pad, vis, minp, mint, cnt, out);
}

// Round 10
// 45.191 us; speedup vs baseline: 1.0397x; 1.0397x over previous
//
#include <hip/hip_runtime.h>

#define NB 2
#define NT 4
#define NN 4096
#define NBT (NB*NT)
#define TOTAL (NBT*NN)        // 32768 points per tensor
#define BIGF 1e10f
#define THRESHF 1e9f
#define NEGF (-1e10f)

typedef __attribute__((ext_vector_type(8)))  short s16x8;
typedef __attribute__((ext_vector_type(16))) float f32x16;

// round-to-nearest-even f32 -> bf16 (raw bits)
__device__ inline unsigned short f2bf(float f) {
    unsigned u = __float_as_uint(f);
    u += 0x7fffu + ((u >> 16) & 1u);
    return (unsigned short)(u >> 16);
}
// split x into bf16 hi + bf16 lo (lo = rn(x - hi)); hi+lo represents x to ~2^-17 rel
__device__ inline void split2(float x, unsigned short& hi, unsigned short& lo) {
    hi = f2bf(x);
    float fh = __uint_as_float(((unsigned)hi) << 16);
    lo = f2bf(x - fh);
}
__device__ inline s16x8 mk8(unsigned short a, unsigned short b, unsigned short c, unsigned short d,
                            unsigned short e, unsigned short f, unsigned short g, unsigned short h) {
    return (s16x8){(short)a,(short)b,(short)c,(short)d,(short)e,(short)f,(short)g,(short)h};
}

// Synthetic K=13 on mfma_f32_32x32x16_bf16 (verified r6/r7/r8, absmax 0.0).
// Row point p (split pa+pb), col point t (u = -2t split ua+ub), wp=||p||^2, wt=||t||^2+bias:
//   row chunk0: pax,pay,paz,pbx,pby,pbz,pax,pay   chunk1: paz,one,one,wph,wpl,0,0,0
//   col chunk0: uax,uay,uaz,uax,uay,uaz,ubx,uby   chunk1: ubz,wth,wtl,one,one,0,0,0
// => D[r,c] = wp + wt - 2 p.t  (lo*lo term dropped, err ~4e-6)
// A/B frag: lane l -> row/col l&31, k-chunk l>>5.
// C/D: col = lane&31, row = (reg&3) + 8*(reg>>2) + 4*(lane>>5)

// ws layout: minp[TOTAL] u32 | mint[TOTAL] u32 | cnt[16] u32  (cnt,out memset0 per call)
//
// Single kernel, grid (64 rc, 16 btdir), 256 thr = 4 waves, ~35 KB LDS, 4 blocks/CU.
// Each block OWNS rows [rc*64, rc*64+64) of its (bt,dir): loops over 4 col-chunks
// (stage 1024 col-packs in LDS -> wave (rt=w&1 row-tile, ch=w>>1 col-half) does
// 8x{2 ds_read + 2 MFMA + 16 v_min3}), then intra-block epilogue -> FINAL row-min,
// published once via atomicExch (coherent RMW, cross-XCD safe; NO fences - r9's
// __threadfence L2-writeback x1024 was the 45us stall).
// Last block of each bt (atomicAdd cnt == 127) runs finalize, reading mins via
// no-op atomicMin(p,0xFFFFFFFF) = coherent RMW read.
__global__ __launch_bounds__(256, 4) void hybrid_kernel(
    const float* __restrict__ pred, const float* __restrict__ targ,
    const int* __restrict__ ic, const int* __restrict__ pad, const int* __restrict__ vis,
    unsigned* __restrict__ minp, unsigned* __restrict__ mint,
    unsigned* __restrict__ cnt, float* __restrict__ out)
{
    __shared__ __align__(16) char ldsraw[32768];   // staging 2048 recs x16B; reused as fbuf
    __shared__ float part[4][64];
    __shared__ float redA[4][5];
    __shared__ float redB[4][4];
    __shared__ int sflag;
    s16x8* ldsB = (s16x8*)ldsraw;

    const int tid  = threadIdx.x;
    const int lane = tid & 63;
    const int w    = tid >> 6;
    const int rc   = blockIdx.x;     // 0..63 : owns rows rc*64..+64
    const int zz   = blockIdx.y;     // 0..15
    const int bt   = zz >> 1;
    const int dir  = zz & 1;
    const int b    = bt >> 2;

    const float* __restrict__ rowraw = dir ? targ : pred;
    const float* __restrict__ colraw = dir ? pred : targ;
    unsigned* outp = dir ? mint : minp;
    const unsigned short one = 0x3F80;

    const int rt = w & 1;            // wave's 32-row tile within the 64 owned rows
    const int ch = w >> 1;           // wave's col half within each staged chunk
    const int h  = lane >> 5;        // k-chunk
    const int c  = lane & 31;        // row/col within tile
    const int rowbase = rc * 64;

    // ---- A fragment (one 32-row tile per wave) ----
    s16x8 a;
    {
        int row = bt*NN + rowbase + rt*32 + c;
        float x = rowraw[3*row], y = rowraw[3*row+1], zc = rowraw[3*row+2];
        unsigned short ax,ay,az,bx,by,bz,wh,wl;
        split2(x,ax,bx); split2(y,ay,by); split2(zc,az,bz);
        float wn = fmaf(x,x, fmaf(y,y, zc*zc));
        split2(wn, wh, wl);
        a = h ? mk8(az,one,one,wh,wl,0,0,0) : mk8(ax,ay,az,bx,by,bz,ax,ay);
    }

    f32x16 zf, mm;
    #pragma unroll
    for (int q = 0; q < 16; ++q) { zf[q] = 0.0f; mm[q] = 3.4e38f; }

    // ---- loop over the 4 column chunks of this (bt,dir) ----
    for (int cc = 0; cc < 4; ++cc) {
        if (cc) __syncthreads();     // previous chunk's reads done before overwrite
        #pragma unroll
        for (int r = 0; r < 4; ++r) {
            int nloc = r*256 + tid;                 // local col 0..1023
            int n    = cc*1024 + nloc;
            int gi   = bt*NN + n;
            bool m = (ic[b*NN + n] == 0) && (pad[b*NN + n] != 0) && (vis[gi] != 0);
            float bias = m ? 0.0f : BIGF;
            float x = colraw[3*gi], y = colraw[3*gi+1], zc = colraw[3*gi+2];
            unsigned short ux,uy,uz,vx,vy,vz,chh,cll;
            split2(-2.0f*x,ux,vx); split2(-2.0f*y,uy,vy); split2(-2.0f*zc,uz,vz);
            float wn = fmaf(x,x, fmaf(y,y, zc*zc));
            split2(wn + bias, chh, cll);
            int tile = nloc >> 5;
            int c32  = tid & 31;
            ldsB[tile*64 + c32]      = mk8(ux,uy,uz,ux,uy,uz,vx,vy);
            ldsB[tile*64 + 32 + c32] = mk8(vz,chh,cll,one,one,0,0,0);
        }
        __syncthreads();

        #pragma unroll 2
        for (int tp = 0; tp < 8; ++tp) {
            s16x8 b0 = ldsB[(ch*16 + 2*tp    )*64 + lane];
            s16x8 b1 = ldsB[(ch*16 + 2*tp + 1)*64 + lane];
            f32x16 D0 = __builtin_amdgcn_mfma_f32_32x32x16_bf16(a, b0, zf, 0, 0, 0);
            f32x16 D1 = __builtin_amdgcn_mfma_f32_32x32x16_bf16(a, b1, zf, 0, 0, 0);
            #pragma unroll
            for (int q = 0; q < 16; ++q)
                mm[q] = fminf(fminf(D0[q], D1[q]), mm[q]);   // v_min3
        }
    }

    // ---- intra-block epilogue: fbuf[2 tiles][32 rows][65] col-partials ----
    __syncthreads();
    float* fbuf = (float*)ldsraw;
    #pragma unroll
    for (int q = 0; q < 16; ++q) {
        int rl = (q & 3) + 8*(q >> 2) + 4*h;
        fbuf[rt*2080 + rl*65 + ch*32 + c] = mm[q];
    }
    __syncthreads();
    {
        int r  = tid & 63;           // row-local 0..63
        int q4 = tid >> 6;           // quarter of the 64 col-partials
        const float* rp = fbuf + (r >> 5)*2080 + (r & 31)*65 + q4*16;
        float v = rp[0];
        #pragma unroll
        for (int k = 1; k < 16; ++k) v = fminf(v, rp[k]);
        part[q4][r] = v;
    }
    __syncthreads();
    if (tid < 64) {
        float v = fminf(fminf(part[0][tid], part[1][tid]), fminf(part[2][tid], part[3][tid]));
        float xv = fmaxf(v, 0.0f);
        unsigned bits = __float_as_uint(xv);
        if (!(xv == xv))         bits = __float_as_uint(BIGF);  // NaN guard
        if (bits == 0x80000000u) bits = 0u;                     // -0 -> +0
        atomicExch(&outp[bt*NN + rowbase + tid], bits);         // coherent publish (RMW)
    }

    // ---- completion count; last of this bt's 128 blocks finalizes ----
    __syncthreads();
    asm volatile("s_waitcnt vmcnt(0)" ::: "memory");   // publishes acked before count
    if (tid == 0) {
        unsigned old = atomicAdd(&cnt[bt], 1u);
        sflag = (old == 127u) ? 1 : 0;
    }
    __syncthreads();
    if (!sflag) return;

    // ---- finalize for this bt: 256 threads x 16 elems; mins read via coherent RMW ----
    float hp[16], ht[16];
    float nv = 0.f, scdp = 0.f, scdt = 0.f, mhp = NEGF, mht = NEGF;
    #pragma unroll
    for (int g = 0; g < 4; ++g) {
        int i4 = tid + g*256;        // int4 record over this bt's 4096 elems
        int4 i4v = ((const int4*)(ic  + b*NN))[i4];
        int4 a4v = ((const int4*)(pad + b*NN))[i4];
        int4 v4v = ((const int4*)(vis + bt*NN))[i4];
        int icv[4]  = { i4v.x, i4v.y, i4v.z, i4v.w };
        int padv[4] = { a4v.x, a4v.y, a4v.z, a4v.w };
        int visv[4] = { v4v.x, v4v.y, v4v.z, v4v.w };
        #pragma unroll
        for (int e = 0; e < 4; ++e) {
            int idx = bt*NN + i4*4 + e;
            unsigned pbits = atomicMin(&minp[idx], 0xFFFFFFFFu);  // no-op RMW read
            unsigned tbits = atomicMin(&mint[idx], 0xFFFFFFFFu);
            bool m = (icv[e] == 0) && (padv[e] != 0) && (visv[e] != 0);
            float mp = __uint_as_float(pbits);
            float mt = __uint_as_float(tbits);
            if (!(mp <= 2e10f)) mp = BIGF;   // NaN/garbage guard
            if (!(mt <= 2e10f)) mt = BIGF;
            float hpv = m ? fminf(mp, THRESHF) : NEGF;
            float htv = m ? fminf(mt, THRESHF) : NEGF;
            hp[g*4+e] = hpv; ht[g*4+e] = htv;
            if (m) {
                nv += 1.f;
                scdp += (mp > THRESHF) ? 0.f : mp;
                scdt += (mt > THRESHF) ? 0.f : mt;
                mhp = fmaxf(mhp, hpv);
                mht = fmaxf(mht, htv);
            }
        }
    }

    #pragma unroll
    for (int o = 32; o > 0; o >>= 1) {
        nv   += __shfl_xor(nv, o);
        scdp += __shfl_xor(scdp, o);
        scdt += __shfl_xor(scdt, o);
        mhp   = fmaxf(mhp, __shfl_xor(mhp, o));
        mht   = fmaxf(mht, __shfl_xor(mht, o));
    }
    if (lane == 0) {
        redA[w][0] = nv; redA[w][1] = scdp; redA[w][2] = scdt;
        redA[w][3] = mhp; redA[w][4] = mht;
    }
    __syncthreads();
    nv   = redA[0][0] + redA[1][0] + redA[2][0] + redA[3][0];
    scdp = redA[0][1] + redA[1][1] + redA[2][1] + redA[3][1];
    scdt = redA[0][2] + redA[1][2] + redA[2][2] + redA[3][2];
    mhp  = fmaxf(fmaxf(redA[0][3], redA[1][3]), fmaxf(redA[2][3], redA[3][3]));
    mht  = fmaxf(fmaxf(redA[0][4], redA[1][4]), fmaxf(redA[2][4], redA[3][4]));
    __syncthreads();

    float Zp = 0.f, Sp = 0.f, Zt = 0.f, St = 0.f;
    #pragma unroll
    for (int k = 0; k < 16; ++k) {
        float hpv = hp[k];
        if (hpv > -THRESHF) { float x = __expf((hpv - mhp) * 10.0f); Zp += x; Sp += hpv * x; }
        float htv = ht[k];
        if (htv > -THRESHF) { float x = __expf((htv - mht) * 10.0f); Zt += x; St += htv * x; }
    }
    #pragma unroll
    for (int o = 32; o > 0; o >>= 1) {
        Zp += __shfl_xor(Zp, o);
        Sp += __shfl_xor(Sp, o);
        Zt += __shfl_xor(Zt, o);
        St += __shfl_xor(St, o);
    }
    if (lane == 0) {
        redB[w][0] = Zp; redB[w][1] = Sp; redB[w][2] = Zt; redB[w][3] = St;
    }
    __syncthreads();
    if (tid == 0) {
        Zp = redB[0][0] + redB[1][0] + redB[2][0] + redB[3][0];
        Sp = redB[0][1] + redB[1][1] + redB[2][1] + redB[3][1];
        Zt = redB[0][2] + redB[1][2] + redB[2][2] + redB[3][2];
        St = redB[0][3] + redB[1][3] + redB[2][3] + redB[3][3];
        float nvm = fmaxf(nv, 1.f);
        float cd  = scdp / nvm + scdt / nvm;
        float sp  = (nv > 0.f) ? (Sp / Zp) : 0.f;
        float st  = (nv > 0.f) ? (St / Zt) : 0.f;
        float hd  = fmaxf(sp, st);
        atomicAdd(out, (0.5f * cd + 0.5f * hd) * 0.125f);
    }
}

extern "C" void kernel_launch(void* const* d_in, const int* in_sizes, int n_in,
                              void* d_out, int out_size, void* d_ws, size_t ws_size,
                              hipStream_t stream)
{
    const float* pred = (const float*)d_in[0];
    const float* targ = (const float*)d_in[1];
    const int*   ic   = (const int*)d_in[2];
    const int*   pad  = (const int*)d_in[3];
    const int*   vis  = (const int*)d_in[4];
    float* out = (float*)d_out;

    unsigned* minp = (unsigned*)d_ws;             // TOTAL u32 (final row-mins, dir0)
    unsigned* mint = minp + TOTAL;                // TOTAL u32 (dir1)
    unsigned* cnt  = mint + TOTAL;                // 16 u32

    hipMemsetAsync(cnt, 0, 16 * 4, stream);       // per-call, graph-capturable
    hipMemsetAsync(out, 0, 4, stream);

    dim3 grid(64, 16);
    hybrid_kernel<<<grid, 256, 0, stream>>>(pred, targ, ic, pad, vis, minp, mint, cnt, out);
}

// Round 11
// 24.637 us; speedup vs baseline: 1.9071x; 1.8342x over previous
//
#include <hip/hip_runtime.h>

#define NB 2
#define NT 4
#define NN 4096
#define NBT (NB*NT)
#define TOTAL (NBT*NN)        // 32768 points per tensor
#define BIGF 1e10f
#define THRESHF 1e9f
#define NEGF (-1e10f)

typedef __attribute__((ext_vector_type(8)))  short s16x8;
typedef __attribute__((ext_vector_type(16))) float f32x16;

// round-to-nearest-even f32 -> bf16 (raw bits)
__device__ inline unsigned short f2bf(float f) {
    unsigned u = __float_as_uint(f);
    u += 0x7fffu + ((u >> 16) & 1u);
    return (unsigned short)(u >> 16);
}
// split x into bf16 hi + bf16 lo (lo = rn(x - hi)); hi+lo represents x to ~2^-17 rel
__device__ inline void split2(float x, unsigned short& hi, unsigned short& lo) {
    hi = f2bf(x);
    float fh = __uint_as_float(((unsigned)hi) << 16);
    lo = f2bf(x - fh);
}
__device__ inline s16x8 mk8(unsigned short a, unsigned short b, unsigned short c, unsigned short d,
                            unsigned short e, unsigned short f, unsigned short g, unsigned short h) {
    return (s16x8){(short)a,(short)b,(short)c,(short)d,(short)e,(short)f,(short)g,(short)h};
}

// Synthetic K=13 on mfma_f32_32x32x16_bf16 (verified r6/r7/r8, absmax 0.0).
// Row point p (split pa+pb), col point t (u = -2t split ua+ub), wp=||p||^2, wt=||t||^2+bias:
//   row chunk0: pax,pay,paz,pbx,pby,pbz,pax,pay   chunk1: paz,one,one,wph,wpl,0,0,0
//   col chunk0: uax,uay,uaz,uax,uay,uaz,ubx,uby   chunk1: ubz,wth,wtl,one,one,0,0,0
// => D[r,c] = wp + wt - 2 p.t  (lo*lo term dropped, err ~4e-6)
// A/B frag: lane l -> row/col l&31, k-chunk l>>5.
// C/D: col = lane&31, row = (reg&3) + 8*(reg>>2) + 4*(lane>>5)
//
// r9/r10 lesson (fused single-kernel): cross-XCD coherence via fences (r9: 1024
// device fences = L2 writebacks) or RMW-atomic reads (r10: 65k latency-bound
// atomicMin round-trips on 8 CUs) costs +25us of stall. Two-kernel structure
// keeps publishes as plain stores and gets coherence from the dispatch boundary.

// Fused min kernel: col packs computed into LDS from raw floats, row packs in regs,
// MFMA row-min over this block's 1024-col quarter, LDS-transpose epilogue,
// plain stores to per-cc partial buffers (each slot written exactly once -> no init).
// grid (4 cc, 16 rc, 16 bt*dir), block 256 = 4 waves; ~34 KB LDS; 4 blocks/CU.
__global__ __launch_bounds__(256, 4) void min_kernel(
    const float* __restrict__ pred, const float* __restrict__ targ,
    const int* __restrict__ ic, const int* __restrict__ pad, const int* __restrict__ vis,
    unsigned* __restrict__ minp, unsigned* __restrict__ mint,
    float* __restrict__ out)
{
    // 2048 B-records (32 KB) for staging; reused as 4x64x33 f32 (33792 B) in epilogue
    __shared__ __align__(16) char ldsraw[33792];
    s16x8* ldsB = (s16x8*)ldsraw;

    const int tid  = threadIdx.x;
    const int lane = tid & 63;
    const int w    = tid >> 6;
    const int cc   = blockIdx.x;
    const int rc   = blockIdx.y;
    const int z    = blockIdx.z;
    const int bt   = z >> 1;
    const int dir  = z & 1;
    const int b    = bt >> 2;
    if (cc == 0 && rc == 0 && z == 0 && tid == 0) out[0] = 0.0f;  // poison-safe zero

    const float* __restrict__ rowraw = dir ? targ : pred;
    const float* __restrict__ colraw = dir ? pred : targ;
    unsigned* outp = (dir ? mint : minp) + cc * TOTAL;
    const unsigned short one = 0x3F80;

    // ---- stage 1024 column packs into LDS (computed from raw floats + mask) ----
    #pragma unroll
    for (int r = 0; r < 4; ++r) {
        int nloc = r*256 + tid;                 // local col 0..1023
        int n    = cc*1024 + nloc;              // col within bt
        int gi   = bt*NN + n;
        bool m = (ic[b*NN + n] == 0) && (pad[b*NN + n] != 0) && (vis[gi] != 0);
        float bias = m ? 0.0f : BIGF;
        float x = colraw[3*gi], y = colraw[3*gi+1], zc = colraw[3*gi+2];
        unsigned short ux,uy,uz,vx,vy,vz,ch,cl;
        split2(-2.0f*x,ux,vx); split2(-2.0f*y,uy,vy); split2(-2.0f*zc,uz,vz);
        float wn = fmaf(x,x, fmaf(y,y, zc*zc));
        split2(wn + bias, ch, cl);
        int tile = nloc >> 5;
        int c32  = tid & 31;                    // == nloc & 31
        ldsB[tile*64 + c32]      = mk8(ux,uy,uz,ux,uy,uz,vx,vy);
        ldsB[tile*64 + 32 + c32] = mk8(vz,ch,cl,one,one,0,0,0);
    }

    // ---- row fragments in registers (2 x 32-row tiles per wave) ----
    const int h  = lane >> 5;       // k-chunk
    const int c  = lane & 31;       // row within tile
    const int n0 = rc*256 + w*64;
    s16x8 a[2];
    #pragma unroll
    for (int rt = 0; rt < 2; ++rt) {
        int row = bt*NN + n0 + rt*32 + c;
        float x = rowraw[3*row], y = rowraw[3*row+1], zc = rowraw[3*row+2];
        unsigned short ax,ay,az,bx,by,bz,wh,wl;
        split2(x,ax,bx); split2(y,ay,by); split2(zc,az,bz);
        float wn = fmaf(x,x, fmaf(y,y, zc*zc));
        split2(wn, wh, wl);
        a[rt] = h ? mk8(az,one,one,wh,wl,0,0,0) : mk8(ax,ay,az,bx,by,bz,ax,ay);
    }

    __syncthreads();

    f32x16 zf, mm[2];
    #pragma unroll
    for (int q = 0; q < 16; ++q) { zf[q] = 0.0f; mm[0][q] = 3.4e38f; mm[1][q] = 3.4e38f; }

    // unroll 2: next iteration's ds_reads issue under this iteration's min3 chain
    #pragma unroll 2
    for (int tp = 0; tp < 16; ++tp) {
        s16x8 b0 = ldsB[tp*128 + lane];
        s16x8 b1 = ldsB[tp*128 + 64 + lane];
        #pragma unroll
        for (int rt = 0; rt < 2; ++rt) {
            f32x16 D0 = __builtin_amdgcn_mfma_f32_32x32x16_bf16(a[rt], b0, zf, 0, 0, 0);
            f32x16 D1 = __builtin_amdgcn_mfma_f32_32x32x16_bf16(a[rt], b1, zf, 0, 0, 0);
            #pragma unroll
            for (int q = 0; q < 16; ++q)
                mm[rt][q] = fminf(fminf(D0[q], D1[q]), mm[rt][q]);   // v_min3
        }
    }

    // ---- LDS-transpose epilogue: wave-private [64 rows][33 stride] f32 region ----
    __syncthreads();                 // everyone done reading staged B
    float* fbuf = (float*)ldsraw;
    const int wbase = w * 2112;      // 64*33
    #pragma unroll
    for (int rt = 0; rt < 2; ++rt) {
        #pragma unroll
        for (int q = 0; q < 16; ++q) {
            int rl = rt*32 + (q & 3) + 8*(q >> 2) + 4*h;   // row-local 0..63
            fbuf[wbase + rl*33 + c] = mm[rt][q];
        }
    }
    // lane l owns row-local l: tree-min its 32 column partials (conflict-free stride 33)
    const float* rowp = fbuf + wbase + lane*33;
    float v = 3.4e38f;
    #pragma unroll
    for (int k = 0; k < 32; ++k) v = fminf(v, rowp[k]);
    float xv = fmaxf(v, 0.0f);
    unsigned bits = __float_as_uint(xv);
    if (!(xv == xv))         bits = __float_as_uint(BIGF);  // NaN guard
    if (bits == 0x80000000u) bits = 0u;                     // -0 -> +0
    outp[bt*NN + n0 + lane] = bits;                         // plain store (slot owned)
}

// one block per (b,t), 1024 threads, 4 elems/thread via uint4/int4 loads; min over 4 cc-partials.
__global__ __launch_bounds__(1024) void finalize_kernel(
    const unsigned* __restrict__ minp, const unsigned* __restrict__ mint,
    const int* __restrict__ ic, const int* __restrict__ pad, const int* __restrict__ vis,
    float* __restrict__ out)
{
    const int bt  = blockIdx.x;
    const int b   = bt >> 2;
    const int tid = threadIdx.x;
    const int S   = TOTAL/4;   // uint4 stride between cc partials

    const uint4* pp = (const uint4*)(minp + bt*NN);
    const uint4* tt = (const uint4*)(mint + bt*NN);
    uint4 p0 = pp[tid], p1 = pp[S + tid], p2 = pp[2*S + tid], p3 = pp[3*S + tid];
    uint4 t0 = tt[tid], t1 = tt[S + tid], t2 = tt[2*S + tid], t3 = tt[3*S + tid];
    int4 ic4  = ((const int4*)(ic  + b*NN))[tid];
    int4 pad4 = ((const int4*)(pad + b*NN))[tid];
    int4 vis4 = ((const int4*)(vis + bt*NN))[tid];

    #define MIN4(a,b,c,d) min(min(a,b), min(c,d))
    unsigned pu[4] = { MIN4(p0.x,p1.x,p2.x,p3.x), MIN4(p0.y,p1.y,p2.y,p3.y),
                       MIN4(p0.z,p1.z,p2.z,p3.z), MIN4(p0.w,p1.w,p2.w,p3.w) };
    unsigned tu[4] = { MIN4(t0.x,t1.x,t2.x,t3.x), MIN4(t0.y,t1.y,t2.y,t3.y),
                       MIN4(t0.z,t1.z,t2.z,t3.z), MIN4(t0.w,t1.w,t2.w,t3.w) };
    #undef MIN4
    int icv[4]  = { ic4.x, ic4.y, ic4.z, ic4.w };
    int padv[4] = { pad4.x, pad4.y, pad4.z, pad4.w };
    int visv[4] = { vis4.x, vis4.y, vis4.z, vis4.w };

    float hp[4], ht[4];
    float nv = 0.f, scdp = 0.f, scdt = 0.f, mhp = NEGF, mht = NEGF;
    #pragma unroll
    for (int e = 0; e < 4; ++e) {
        bool m = (icv[e] == 0) && (padv[e] != 0) && (visv[e] != 0);
        float mp = __uint_as_float(pu[e]);
        float mt = __uint_as_float(tu[e]);
        if (!(mp <= 2e10f)) mp = BIGF;   // NaN/garbage guard
        if (!(mt <= 2e10f)) mt = BIGF;
        float hpv = m ? fminf(mp, THRESHF) : NEGF;
        float htv = m ? fminf(mt, THRESHF) : NEGF;
        hp[e] = hpv; ht[e] = htv;
        if (m) {
            nv += 1.f;
            scdp += (mp > THRESHF) ? 0.f : mp;
            scdt += (mt > THRESHF) ? 0.f : mt;
            mhp = fmaxf(mhp, hpv);
            mht = fmaxf(mht, htv);
        }
    }

    __shared__ float red[16][5];
    const int wid = tid >> 6;
    #pragma unroll
    for (int o = 32; o > 0; o >>= 1) {
        nv   += __shfl_xor(nv, o);
        scdp += __shfl_xor(scdp, o);
        scdt += __shfl_xor(scdt, o);
        mhp   = fmaxf(mhp, __shfl_xor(mhp, o));
        mht   = fmaxf(mht, __shfl_xor(mht, o));
    }
    if ((tid & 63) == 0) {
        red[wid][0] = nv; red[wid][1] = scdp; red[wid][2] = scdt;
        red[wid][3] = mhp; red[wid][4] = mht;
    }
    __syncthreads();
    nv = 0.f; scdp = 0.f; scdt = 0.f; mhp = NEGF; mht = NEGF;
    #pragma unroll
    for (int k = 0; k < 16; ++k) {
        nv += red[k][0]; scdp += red[k][1]; scdt += red[k][2];
        mhp = fmaxf(mhp, red[k][3]); mht = fmaxf(mht, red[k][4]);
    }
    __syncthreads();

    float Zp = 0.f, Sp = 0.f, Zt = 0.f, St = 0.f;
    #pragma unroll
    for (int e = 0; e < 4; ++e) {
        float hpv = hp[e];
        if (hpv > -THRESHF) { float x = __expf((hpv - mhp) * 10.0f); Zp += x; Sp += hpv * x; }
        float htv = ht[e];
        if (htv > -THRESHF) { float x = __expf((htv - mht) * 10.0f); Zt += x; St += htv * x; }
    }
    #pragma unroll
    for (int o = 32; o > 0; o >>= 1) {
        Zp += __shfl_xor(Zp, o);
        Sp += __shfl_xor(Sp, o);
        Zt += __shfl_xor(Zt, o);
        St += __shfl_xor(St, o);
    }
    __shared__ float red2[16][4];
    if ((tid & 63) == 0) {
        red2[wid][0] = Zp; red2[wid][1] = Sp; red2[wid][2] = Zt; red2[wid][3] = St;
    }
    __syncthreads();
    if (tid == 0) {
        Zp = 0.f; Sp = 0.f; Zt = 0.f; St = 0.f;
        #pragma unroll
        for (int k = 0; k < 16; ++k) {
            Zp += red2[k][0]; Sp += red2[k][1]; Zt += red2[k][2]; St += red2[k][3];
        }
        float nvm = fmaxf(nv, 1.f);
        float cd  = scdp / nvm + scdt / nvm;
        float sp  = (nv > 0.f) ? (Sp / Zp) : 0.f;
        float st  = (nv > 0.f) ? (St / Zt) : 0.f;
        float hd  = fmaxf(sp, st);
        atomicAdd(out, (0.5f * cd + 0.5f * hd) * 0.125f);
    }
}

extern "C" void kernel_launch(void* const* d_in, const int* in_sizes, int n_in,
                              void* d_out, int out_size, void* d_ws, size_t ws_size,
                              hipStream_t stream)
{
    const float* pred = (const float*)d_in[0];
    const float* targ = (const float*)d_in[1];
    const int*   ic   = (const int*)d_in[2];
    const int*   pad  = (const int*)d_in[3];
    const int*   vis  = (const int*)d_in[4];
    float* out = (float*)d_out;

    unsigned* minp = (unsigned*)d_ws;                 // 4*TOTAL partial mins (cc0..cc3)
    unsigned* mint = minp + 4*TOTAL;                  // 4*TOTAL

    dim3 grid(4, 16, 16);
    min_kernel<<<grid, 256, 0, stream>>>(pred, targ, ic, pad, vis, minp, mint, out);
    finalize_kernel<<<NBT, 1024, 0, stream>>>(minp, mint, ic, pad, vis, out);
}

// Round 12
// 22.805 us; speedup vs baseline: 2.0604x; 1.0803x over previous
//
#include <hip/hip_runtime.h>

#define NB 2
#define NT 4
#define NN 4096
#define NBT (NB*NT)
#define TOTAL (NBT*NN)        // 32768 points per tensor
#define BIGF 1e10f
#define THRESHF 1e9f
#define NEGF (-1e10f)

typedef __attribute__((ext_vector_type(8)))  short s16x8;
typedef __attribute__((ext_vector_type(16))) float f32x16;

// round-to-nearest-even f32 -> bf16 (raw bits)
__device__ inline unsigned short f2bf(float f) {
    unsigned u = __float_as_uint(f);
    u += 0x7fffu + ((u >> 16) & 1u);
    return (unsigned short)(u >> 16);
}
// split x into bf16 hi + bf16 lo (lo = rn(x - hi)); hi+lo represents x to ~2^-17 rel
__device__ inline void split2(float x, unsigned short& hi, unsigned short& lo) {
    hi = f2bf(x);
    float fh = __uint_as_float(((unsigned)hi) << 16);
    lo = f2bf(x - fh);
}
__device__ inline s16x8 mk8(unsigned short a, unsigned short b, unsigned short c, unsigned short d,
                            unsigned short e, unsigned short f, unsigned short g, unsigned short h) {
    return (s16x8){(short)a,(short)b,(short)c,(short)d,(short)e,(short)f,(short)g,(short)h};
}

// Synthetic K=13 on mfma_f32_32x32x16_bf16 (verified r6/r7/r8, absmax 0.0).
// Row point p (split pa+pb), col point t (u = -2t split ua+ub), wp=||p||^2, wt=||t||^2+bias:
//   row chunk0: pax,pay,paz,pbx,pby,pbz,pax,pay   chunk1: paz,one,one,wph,wpl,0,0,0
//   col chunk0: uax,uay,uaz,uax,uay,uaz,ubx,uby   chunk1: ubz,wth,wtl,one,one,0,0,0
// => D[r,c] = wp + wt - 2 p.t  (lo*lo term dropped, err ~4e-6)
// A/B frag: lane l -> row/col l&31, k-chunk l>>5.
// C/D: col = lane&31, row = (reg&3) + 8*(reg>>2) + 4*(lane>>5)
//
// Structure notes (r9-r11 lessons): two-kernel pipeline; cross-block combine via
// plain stores to per-cc partials (each slot written once, no init dispatch);
// coherence from the dispatch boundary. Fences (r9) and RMW-read fusion (r10)
// each cost +25us of cross-XCD stall. tp-loop unroll 2 (r11) was -1us: keep unroll 1.

// Fused min kernel: col packs computed into LDS from raw floats, row packs in regs,
// MFMA row-min over this block's 1024-col quarter, LDS-transpose epilogue,
// plain stores to per-cc partial buffers.
// grid (4 cc, 16 rc, 16 bt*dir), block 256 = 4 waves; ~34 KB LDS; 4 blocks/CU.
__global__ __launch_bounds__(256, 4) void min_kernel(
    const float* __restrict__ pred, const float* __restrict__ targ,
    const int* __restrict__ ic, const int* __restrict__ pad, const int* __restrict__ vis,
    unsigned* __restrict__ minp, unsigned* __restrict__ mint,
    float* __restrict__ out)
{
    // 2048 B-records (32 KB) for staging; reused as 4x64x33 f32 (33792 B) in epilogue
    __shared__ __align__(16) char ldsraw[33792];
    s16x8* ldsB = (s16x8*)ldsraw;

    const int tid  = threadIdx.x;
    const int lane = tid & 63;
    const int w    = tid >> 6;
    const int cc   = blockIdx.x;
    const int rc   = blockIdx.y;
    const int z    = blockIdx.z;
    const int bt   = z >> 1;
    const int dir  = z & 1;
    const int b    = bt >> 2;
    if (cc == 0 && rc == 0 && z == 0 && tid == 0) out[0] = 0.0f;  // poison-safe zero

    const float* __restrict__ rowraw = dir ? targ : pred;
    const float* __restrict__ colraw = dir ? pred : targ;
    unsigned* outp = (dir ? mint : minp) + cc * TOTAL;
    const unsigned short one = 0x3F80;

    // ---- stage 1024 column packs into LDS; thread owns 4 CONSECUTIVE cols ----
    // masks: 3x int4; coords: 12 contiguous floats = 3x aligned float4 (48B @ 48*t)
    {
        int nl0 = tid * 4;                       // local col base 0..1020
        int n   = cc*1024 + nl0;                 // col within bt (mult of 4)
        int gi  = bt*NN + n;
        int4 icv = *(const int4*)(ic  + b*NN + n);
        int4 pdv = *(const int4*)(pad + b*NN + n);
        int4 vsv = *(const int4*)(vis + gi);
        float4 f0 = *(const float4*)(colraw + 3*gi);
        float4 f1 = *(const float4*)(colraw + 3*gi + 4);
        float4 f2 = *(const float4*)(colraw + 3*gi + 8);
        float cx[4] = { f0.x, f0.w, f1.z, f2.y };
        float cy[4] = { f0.y, f1.x, f1.w, f2.z };
        float cz[4] = { f0.z, f1.y, f2.x, f2.w };
        int   mi[4] = { (icv.x==0)&&(pdv.x!=0)&&(vsv.x!=0), (icv.y==0)&&(pdv.y!=0)&&(vsv.y!=0),
                        (icv.z==0)&&(pdv.z!=0)&&(vsv.z!=0), (icv.w==0)&&(pdv.w!=0)&&(vsv.w!=0) };
        const int tile = nl0 >> 5;               // all 4 cols in same 32-col tile
        const int c32b = nl0 & 31;
        #pragma unroll
        for (int j = 0; j < 4; ++j) {
            float bias = mi[j] ? 0.0f : BIGF;
            float x = cx[j], y = cy[j], zc = cz[j];
            unsigned short ux,uy,uz,vx,vy,vz,ch,cl;
            split2(-2.0f*x,ux,vx); split2(-2.0f*y,uy,vy); split2(-2.0f*zc,uz,vz);
            float wn = fmaf(x,x, fmaf(y,y, zc*zc));
            split2(wn + bias, ch, cl);
            ldsB[tile*64 + c32b + j]      = mk8(ux,uy,uz,ux,uy,uz,vx,vy);
            ldsB[tile*64 + 32 + c32b + j] = mk8(vz,ch,cl,one,one,0,0,0);
        }
    }

    // ---- row fragments in registers (2 x 32-row tiles per wave) ----
    const int h  = lane >> 5;       // k-chunk
    const int c  = lane & 31;       // row within tile
    const int n0 = rc*256 + w*64;
    s16x8 a[2];
    #pragma unroll
    for (int rt = 0; rt < 2; ++rt) {
        int row = bt*NN + n0 + rt*32 + c;
        float x = rowraw[3*row], y = rowraw[3*row+1], zc = rowraw[3*row+2];
        unsigned short ax,ay,az,bx,by,bz,wh,wl;
        split2(x,ax,bx); split2(y,ay,by); split2(zc,az,bz);
        float wn = fmaf(x,x, fmaf(y,y, zc*zc));
        split2(wn, wh, wl);
        a[rt] = h ? mk8(az,one,one,wh,wl,0,0,0) : mk8(ax,ay,az,bx,by,bz,ax,ay);
    }

    __syncthreads();

    f32x16 zf, mm[2];
    #pragma unroll
    for (int q = 0; q < 16; ++q) { zf[q] = 0.0f; mm[0][q] = 3.4e38f; mm[1][q] = 3.4e38f; }

    #pragma unroll 1
    for (int tp = 0; tp < 16; ++tp) {
        s16x8 b0 = ldsB[tp*128 + lane];
        s16x8 b1 = ldsB[tp*128 + 64 + lane];
        #pragma unroll
        for (int rt = 0; rt < 2; ++rt) {
            f32x16 D0 = __builtin_amdgcn_mfma_f32_32x32x16_bf16(a[rt], b0, zf, 0, 0, 0);
            f32x16 D1 = __builtin_amdgcn_mfma_f32_32x32x16_bf16(a[rt], b1, zf, 0, 0, 0);
            #pragma unroll
            for (int q = 0; q < 16; ++q)
                mm[rt][q] = fminf(fminf(D0[q], D1[q]), mm[rt][q]);   // v_min3
        }
    }

    // ---- LDS-transpose epilogue: wave-private [64 rows][33 stride] f32 region ----
    __syncthreads();                 // everyone done reading staged B
    float* fbuf = (float*)ldsraw;
    const int wbase = w * 2112;      // 64*33
    #pragma unroll
    for (int rt = 0; rt < 2; ++rt) {
        #pragma unroll
        for (int q = 0; q < 16; ++q) {
            int rl = rt*32 + (q & 3) + 8*(q >> 2) + 4*h;   // row-local 0..63
            fbuf[wbase + rl*33 + c] = mm[rt][q];
        }
    }
    // lane l owns row-local l: tree-min its 32 column partials (conflict-free stride 33)
    const float* rowp = fbuf + wbase + lane*33;
    float v = 3.4e38f;
    #pragma unroll
    for (int k = 0; k < 32; ++k) v = fminf(v, rowp[k]);
    float xv = fmaxf(v, 0.0f);
    unsigned bits = __float_as_uint(xv);
    if (!(xv == xv))         bits = __float_as_uint(BIGF);  // NaN guard
    if (bits == 0x80000000u) bits = 0u;                     // -0 -> +0
    outp[bt*NN + n0 + lane] = bits;                         // plain store (slot owned)
}

// one block per (b,t), 1024 threads, 4 elems/thread via uint4/int4 loads; min over 4 cc-partials.
__global__ __launch_bounds__(1024) void finalize_kernel(
    const unsigned* __restrict__ minp, const unsigned* __restrict__ mint,
    const int* __restrict__ ic, const int* __restrict__ pad, const int* __restrict__ vis,
    float* __restrict__ out)
{
    const int bt  = blockIdx.x;
    const int b   = bt >> 2;
    const int tid = threadIdx.x;
    const int S   = TOTAL/4;   // uint4 stride between cc partials

    const uint4* pp = (const uint4*)(minp + bt*NN);
    const uint4* tt = (const uint4*)(mint + bt*NN);
    uint4 p0 = pp[tid], p1 = pp[S + tid], p2 = pp[2*S + tid], p3 = pp[3*S + tid];
    uint4 t0 = tt[tid], t1 = tt[S + tid], t2 = tt[2*S + tid], t3 = tt[3*S + tid];
    int4 ic4  = ((const int4*)(ic  + b*NN))[tid];
    int4 pad4 = ((const int4*)(pad + b*NN))[tid];
    int4 vis4 = ((const int4*)(vis + bt*NN))[tid];

    #define MIN4(a,b,c,d) min(min(a,b), min(c,d))
    unsigned pu[4] = { MIN4(p0.x,p1.x,p2.x,p3.x), MIN4(p0.y,p1.y,p2.y,p3.y),
                       MIN4(p0.z,p1.z,p2.z,p3.z), MIN4(p0.w,p1.w,p2.w,p3.w) };
    unsigned tu[4] = { MIN4(t0.x,t1.x,t2.x,t3.x), MIN4(t0.y,t1.y,t2.y,t3.y),
                       MIN4(t0.z,t1.z,t2.z,t3.z), MIN4(t0.w,t1.w,t2.w,t3.w) };
    #undef MIN4
    int icv[4]  = { ic4.x, ic4.y, ic4.z, ic4.w };
    int padv[4] = { pad4.x, pad4.y, pad4.z, pad4.w };
    int visv[4] = { vis4.x, vis4.y, vis4.z, vis4.w };

    float hp[4], ht[4];
    float nv = 0.f, scdp = 0.f, scdt = 0.f, mhp = NEGF, mht = NEGF;
    #pragma unroll
    for (int e = 0; e < 4; ++e) {
        bool m = (icv[e] == 0) && (padv[e] != 0) && (visv[e] != 0);
        float mp = __uint_as_float(pu[e]);
        float mt = __uint_as_float(tu[e]);
        if (!(mp <= 2e10f)) mp = BIGF;   // NaN/garbage guard
        if (!(mt <= 2e10f)) mt = BIGF;
        float hpv = m ? fminf(mp, THRESHF) : NEGF;
        float htv = m ? fminf(mt, THRESHF) : NEGF;
        hp[e] = hpv; ht[e] = htv;
        if (m) {
            nv += 1.f;
            scdp += (mp > THRESHF) ? 0.f : mp;
            scdt += (mt > THRESHF) ? 0.f : mt;
            mhp = fmaxf(mhp, hpv);
            mht = fmaxf(mht, htv);
        }
    }

    __shared__ float red[16][5];
    const int wid = tid >> 6;
    #pragma unroll
    for (int o = 32; o > 0; o >>= 1) {
        nv   += __shfl_xor(nv, o);
        scdp += __shfl_xor(scdp, o);
        scdt += __shfl_xor(scdt, o);
        mhp   = fmaxf(mhp, __shfl_xor(mhp, o));
        mht   = fmaxf(mht, __shfl_xor(mht, o));
    }
    if ((tid & 63) == 0) {
        red[wid][0] = nv; red[wid][1] = scdp; red[wid][2] = scdt;
        red[wid][3] = mhp; red[wid][4] = mht;
    }
    __syncthreads();
    nv = 0.f; scdp = 0.f; scdt = 0.f; mhp = NEGF; mht = NEGF;
    #pragma unroll
    for (int k = 0; k < 16; ++k) {
        nv += red[k][0]; scdp += red[k][1]; scdt += red[k][2];
        mhp = fmaxf(mhp, red[k][3]); mht = fmaxf(mht, red[k][4]);
    }
    __syncthreads();

    float Zp = 0.f, Sp = 0.f, Zt = 0.f, St = 0.f;
    #pragma unroll
    for (int e = 0; e < 4; ++e) {
        float hpv = hp[e];
        if (hpv > -THRESHF) { float x = __expf((hpv - mhp) * 10.0f); Zp += x; Sp += hpv * x; }
        float htv = ht[e];
        if (htv > -THRESHF) { float x = __expf((htv - mht) * 10.0f); Zt += x; St += htv * x; }
    }
    #pragma unroll
    for (int o = 32; o > 0; o >>= 1) {
        Zp += __shfl_xor(Zp, o);
        Sp += __shfl_xor(Sp, o);
        Zt += __shfl_xor(Zt, o);
        St += __shfl_xor(St, o);
    }
    __shared__ float red2[16][4];
    if ((tid & 63) == 0) {
        red2[wid][0] = Zp; red2[wid][1] = Sp; red2[wid][2] = Zt; red2[wid][3] = St;
    }
    __syncthreads();
    if (tid == 0) {
        Zp = 0.f; Sp = 0.f; Zt = 0.f; St = 0.f;
        #pragma unroll
        for (int k = 0; k < 16; ++k) {
            Zp += red2[k][0]; Sp += red2[k][1]; Zt += red2[k][2]; St += red2[k][3];
        }
        float nvm = fmaxf(nv, 1.f);
        float cd  = scdp / nvm + scdt / nvm;
        float sp  = (nv > 0.f) ? (Sp / Zp) : 0.f;
        float st  = (nv > 0.f) ? (St / Zt) : 0.f;
        float hd  = fmaxf(sp, st);
        atomicAdd(out, (0.5f * cd + 0.5f * hd) * 0.125f);
    }
}

extern "C" void kernel_launch(void* const* d_in, const int* in_sizes, int n_in,
                              void* d_out, int out_size, void* d_ws, size_t ws_size,
                              hipStream_t stream)
{
    const float* pred = (const float*)d_in[0];
    const float* targ = (const float*)d_in[1];
    const int*   ic   = (const int*)d_in[2];
    const int*   pad  = (const int*)d_in[3];
    const int*   vis  = (const int*)d_in[4];
    float* out = (float*)d_out;

    unsigned* minp = (unsigned*)d_ws;                 // 4*TOTAL partial mins (cc0..cc3)
    unsigned* mint = minp + 4*TOTAL;                  // 4*TOTAL

    dim3 grid(4, 16, 16);
    min_kernel<<<grid, 256, 0, stream>>>(pred, targ, ic, pad, vis, minp, mint, out);
    finalize_kernel<<<NBT, 1024, 0, stream>>>(minp, mint, ic, pad, vis, out);
}